// Round 1
// baseline (109.574 us; speedup 1.0000x reference)
//
#include <hip/hip_runtime.h>

#define NQ 4
#define DIM 16

// One kernel: threads 0..15 of each block build the fixed weight-circuit
// unitary W (16x16 complex) in registers (all loops fully unrolled ->
// compile-time indices, no scratch), store it transposed in LDS; then every
// thread processes one batch element:
//   sx = product state from RX(x) on |0>  (each amplitude purely real or imag)
//   final = W @ sx   (512 FMAs using the real/imag-only structure)
//   out[q] = sum_i sign_q(i) * |final_i|^2
__global__ void __launch_bounds__(256)
qlayer_kernel(const float4* __restrict__ x,
              const float* __restrict__ weights,
              float4* __restrict__ out, int B)
{
    // WT[j][i] = <i| U_w |j>  (column j contiguous -> float4 LDS reads)
    __shared__ __align__(16) float2 WT[DIM][DIM];

    if (threadIdx.x < DIM) {
        const int k = threadIdx.x;
        float sre[DIM], sim[DIM];
#pragma unroll
        for (int i = 0; i < DIM; ++i) { sre[i] = (i == k) ? 1.f : 0.f; sim[i] = 0.f; }
#pragma unroll
        for (int l = 0; l < 3; ++l) {
            // RX(weights[l][p]) on qubit p  (qubit p <-> bit (3-p))
#pragma unroll
            for (int p = 0; p < NQ; ++p) {
                float c, s;
                __sincosf(0.5f * weights[l * NQ + p], &s, &c);
                const int mask = 1 << (NQ - 1 - p);
#pragma unroll
                for (int i = 0; i < DIM; ++i) {
                    if (i & mask) continue;
                    const int jj = i | mask;
                    const float ar = sre[i], ai = sim[i];
                    const float br = sre[jj], bi = sim[jj];
                    // new0 = c*a - i s*b ; new1 = -i s*a + c*b
                    sre[i]  = c * ar + s * bi;
                    sim[i]  = c * ai - s * br;
                    sre[jj] = c * br + s * ai;
                    sim[jj] = c * bi - s * ar;
                }
            }
            // CNOT ring: new[i] = old[perm[i]], perm[i] = i ^ (ctrl_bit << (3-t))
#pragma unroll
            for (int p = 0; p < NQ; ++p) {
                const int t = (p + 1) % NQ;
                float tr[DIM], ti[DIM];
#pragma unroll
                for (int i = 0; i < DIM; ++i) {
                    const int src = i ^ ((((i >> (NQ - 1 - p)) & 1)) << (NQ - 1 - t));
                    tr[i] = sre[src]; ti[i] = sim[src];
                }
#pragma unroll
                for (int i = 0; i < DIM; ++i) { sre[i] = tr[i]; sim[i] = ti[i]; }
            }
        }
#pragma unroll
        for (int i = 0; i < DIM; ++i) WT[k][i] = make_float2(sre[i], sim[i]);
    }
    __syncthreads();

    const int b = blockIdx.x * blockDim.x + threadIdx.x;
    if (b >= B) return;

    const float4 xv = x[b];
    float c0, s0, c1, s1, c2, s2, c3, s3;
    __sincosf(0.5f * xv.x, &s0, &c0);
    __sincosf(0.5f * xv.y, &s1, &c1);
    __sincosf(0.5f * xv.z, &s2, &c2);
    __sincosf(0.5f * xv.w, &s3, &c3);

    // r_j = prod_q (bit_q(j) ? s_q : c_q); qubit q <-> bit (3-q)
    const float hh[4] = {c0 * c1, c0 * s1, s0 * c1, s0 * s1}; // bits (3,2) = qubits 0,1
    const float ll[4] = {c2 * c3, c2 * s3, s2 * c3, s2 * s3}; // bits (1,0) = qubits 2,3

    float fr[DIM], fi[DIM];
#pragma unroll
    for (int i = 0; i < DIM; ++i) { fr[i] = 0.f; fi[i] = 0.f; }

#pragma unroll
    for (int j = 0; j < DIM; ++j) {
        const float r = hh[j >> 2] * ll[j & 3];
        const int pc = __builtin_popcount(j);   // folds: j is a constant after unroll
        const float4* __restrict__ w4 = (const float4*)(&WT[j][0]);
        if ((pc & 1) == 0) {
            // sx_j = v (real), v = (-1)^(pc/2) * r
            const float v = (pc & 2) ? -r : r;
#pragma unroll
            for (int m = 0; m < 8; ++m) {
                const float4 w = w4[m];   // (re_i, im_i, re_{i+1}, im_{i+1})
                fr[2 * m]     += w.x * v;  fi[2 * m]     += w.y * v;
                fr[2 * m + 1] += w.z * v;  fi[2 * m + 1] += w.w * v;
            }
        } else {
            // sx_j = i*v, v = (pc%4==3) ? +r : -r;  w*(i v) = -im*v + i re*v
            const float v = (pc & 2) ? r : -r;
#pragma unroll
            for (int m = 0; m < 8; ++m) {
                const float4 w = w4[m];
                fr[2 * m]     -= w.y * v;  fi[2 * m]     += w.x * v;
                fr[2 * m + 1] -= w.w * v;  fi[2 * m + 1] += w.z * v;
            }
        }
    }

    float o0 = 0.f, o1 = 0.f, o2 = 0.f, o3 = 0.f;
#pragma unroll
    for (int i = 0; i < DIM; ++i) {
        const float p = fr[i] * fr[i] + fi[i] * fi[i];
        o0 += (i & 8) ? -p : p;   // output q <-> bit (3-q)
        o1 += (i & 4) ? -p : p;
        o2 += (i & 2) ? -p : p;
        o3 += (i & 1) ? -p : p;
    }
    out[b] = make_float4(o0, o1, o2, o3);
}

extern "C" void kernel_launch(void* const* d_in, const int* in_sizes, int n_in,
                              void* d_out, int out_size, void* d_ws, size_t ws_size,
                              hipStream_t stream)
{
    const float4* x = (const float4*)d_in[0];
    const float* w  = (const float*)d_in[1];
    float4* out     = (float4*)d_out;
    const int B = in_sizes[0] / NQ;
    const int block = 256;
    const int grid = (B + block - 1) / block;
    qlayer_kernel<<<grid, block, 0, stream>>>(x, w, out, B);
}